// Round 1
// 244.485 us; speedup vs baseline: 1.0495x; 1.0495x over previous
//
#include <hip/hip_runtime.h>

// MakeCutouts: 32 cutouts of (8,3,512,512) fp32 -> adaptive avg pool 224x224.
//
// R4: VALU-bound (VALUBusy 65%, HBM writes only 1.2 TB/s, reads L3-served).
// Kill per-pixel bin math: per-block LDS tables hold (sq|wq, invq) for all
// 224 q and (sp|wp, invp) for the block's 4 p -> one ds_read_b64 + 2 unpacks
// replaces ~25 VALU ops/pixel. Tile shrunk to TILE_P=2 (6 staged rows,
// 14.4 KB) so tile+tables = 16.2 KB -> 8 blocks/CU = 32 waves (100% occ).
// Each block does 2 bands (4 output rows, same 43008-block grid as R3);
// band-B global loads are issued into registers before pool-A (latency
// hidden under compute), written to LDS after pool-A's barrier.

constexpr int OUTSZ = 224;
constexpr int BB    = 8;
constexpr int CC    = 3;
constexpr int HH    = 512;
constexpr int WW    = 512;
constexpr int CUTN  = 32;

constexpr int PAIR   = 4;             // output rows per block (2 bands x 2)
constexpr int NPAIR  = OUTSZ / PAIR;  // 56
// Per band (TILE_P=2): staged rows nr <= ceil(2*512/224)+1 = 6 (rows 0..5).
// Masked window reads reach row sp+3 <= ceil(1*512/224)+3 = 6 and col
// x0+sq+3 <= 514 -> allocate rows 0..6, last index 6*512+514.
constexpr int LDSF    = 6 * WW + 516;            // 3588 floats = 14352 B
constexpr int NBLOCKS = CUTN * BB * CC * NPAIR;  // 43008

// Pool one band of 2x224 pixels using precomputed bin tables.
// qtab[q] = { sq | wq<<12 , bits(1/wq) }; ptab[pbase+lp] similar for rows.
template <int WIN>
__device__ __forceinline__ void pool_band(const float* __restrict__ tile,
                                          const uint2* __restrict__ qtab,
                                          const uint2* __restrict__ ptab,
                                          int pbase,
                                          float* __restrict__ outp,
                                          int x0)
{
#pragma unroll
    for (int it = 0; it < 2; ++it) {
        int jj = threadIdx.x + it * 256;
        if (jj < 2 * OUTSZ) {
            int lp = (jj >= OUTSZ) ? 1 : 0;
            int q  = jj - lp * OUTSZ;

            uint2 qe = qtab[q];
            int sq = qe.x & 1023;
            int wq = qe.x >> 12;
            uint2 pe = ptab[pbase + lp];
            int sp = pe.x & 1023;
            int wp = pe.x >> 12;

            const float* t0 = tile + sp * WW + x0 + sq;
            float z = 0.0f;
            float rowsum[WIN];
#pragma unroll
            for (int r = 0; r < WIN; ++r) {
                const float* tr = t0 + r * WW;
                // adjacent cols -> ds_read2_b32; masked lanes add z (no
                // garbage propagation; reads stay inside the LDS pad).
                float s = tr[0];
#pragma unroll
                for (int k = 1; k < WIN; ++k)
                    s += (wq > k) ? tr[k] : z;
                rowsum[r] = s;
            }
            float sum = rowsum[0];
#pragma unroll
            for (int r = 1; r < WIN; ++r)
                sum += (wp > r) ? rowsum[r] : z;

            outp[jj] = sum * __uint_as_float(qe.y) * __uint_as_float(pe.y);
        }
    }
}

__global__ __launch_bounds__(256, 8) void make_cutouts_kernel(
    const float* __restrict__ x,
    const int*   __restrict__ sizes,
    const int*   __restrict__ offy,
    const int*   __restrict__ offx,
    float*       __restrict__ out)
{
    __shared__ float tile[LDSF];
    __shared__ uint2 qtab[OUTSZ];  // 1792 B
    __shared__ uint2 ptab[PAIR];   // 32 B   (total LDS ~16.2 KB -> 8 blk/CU)

    int gid = blockIdx.x;
    int tp  = gid % NPAIR;  int t = gid / NPAIR;
    int c   = t % CC;       t /= CC;
    int b   = t % BB;
    int i   = t / BB;

    // block-uniform per-cutout params -> scalar broadcast
    int S  = sizes[i];
    int y0 = offy[i];
    int x0 = offx[i];
    int p0 = tp * PAIR;

    // Band A = output rows p0..p0+1, band B = p0+2..p0+3.
    int r0A = (p0 * S) / OUTSZ;
    int r1A = ((p0 + 2) * S + OUTSZ - 1) / OUTSZ;
    int nrA = r1A - r0A;                          // 2..6
    int r0B = ((p0 + 2) * S) / OUTSZ;
    int r1B = ((p0 + 4) * S + OUTSZ - 1) / OUTSZ;
    int nrB = r1B - r0B;                          // 2..6

    const float* plane = x + (size_t)((b * CC + c) * HH + y0) * WW;
    const float4* srcA = (const float4*)(plane + (size_t)r0A * WW);
    const float4* srcB = (const float4*)(plane + (size_t)r0B * WW);
    float4* tile4 = (float4*)tile;
    int tid = threadIdx.x;

    // ---- issue band-A staging loads (full 512-wide rows, contiguous) ----
    int n4A = nrA * (WW / 4);                     // >= 256 always
    float4 a0, a1, a2;
    a0 = srcA[tid];
    bool am1 = (tid + 256 < n4A), am2 = (tid + 512 < n4A);
    if (am1) a1 = srcA[tid + 256];
    if (am2) a2 = srcA[tid + 512];

    // ---- build bin tables while the loads are in flight ----
    if (tid < OUTSZ) {
        int sq = (tid * S) / OUTSZ;
        int wq = ((tid + 1) * S + OUTSZ - 1) / OUTSZ - sq;   // 1..4
        float inv = (wq == 1) ? 1.0f : (wq == 2) ? 0.5f
                  : (wq == 3) ? (1.0f / 3.0f) : 0.25f;
        qtab[tid] = make_uint2((unsigned)(sq | (wq << 12)),
                               __float_as_uint(inv));
    } else if (tid < OUTSZ + PAIR) {
        int k  = tid - OUTSZ;                     // 0..3
        int p  = p0 + k;
        int r0 = (k < 2) ? r0A : r0B;
        int spAbs = (p * S) / OUTSZ;
        int wp = ((p + 1) * S + OUTSZ - 1) / OUTSZ - spAbs;  // 1..4
        float inv = (wp == 1) ? 1.0f : (wp == 2) ? 0.5f
                  : (wp == 3) ? (1.0f / 3.0f) : 0.25f;
        ptab[k] = make_uint2((unsigned)((spAbs - r0) | (wp << 12)),
                             __float_as_uint(inv));
    }

    // ---- band-A LDS write + barrier ----
    tile4[tid] = a0;
    if (am1) tile4[tid + 256] = a1;
    if (am2) tile4[tid + 512] = a2;
    __syncthreads();

    float* outp = out + ((size_t)((i * BB + b) * CC + c) * OUTSZ + p0) * OUTSZ;

    // ---- issue band-B loads NOW; latency hides under pool-A compute ----
    int n4B = nrB * (WW / 4);
    float4 b0, b1, b2;
    b0 = srcB[tid];
    bool bm1 = (tid + 256 < n4B), bm2 = (tid + 512 < n4B);
    if (bm1) b1 = srcB[tid + 256];
    if (bm2) b2 = srcB[tid + 512];

    if (S <= 2 * OUTSZ) {   // block-uniform: max bin width 3
        pool_band<3>(tile, qtab, ptab, 0, outp, x0);
        __syncthreads();
        tile4[tid] = b0;
        if (bm1) tile4[tid + 256] = b1;
        if (bm2) tile4[tid + 512] = b2;
        __syncthreads();
        pool_band<3>(tile, qtab, ptab, 2, outp + 2 * OUTSZ, x0);
    } else {                // S in (448,512]: max bin width 4
        pool_band<4>(tile, qtab, ptab, 0, outp, x0);
        __syncthreads();
        tile4[tid] = b0;
        if (bm1) tile4[tid + 256] = b1;
        if (bm2) tile4[tid + 512] = b2;
        __syncthreads();
        pool_band<4>(tile, qtab, ptab, 2, outp + 2 * OUTSZ, x0);
    }
}

extern "C" void kernel_launch(void* const* d_in, const int* in_sizes, int n_in,
                              void* d_out, int out_size, void* d_ws, size_t ws_size,
                              hipStream_t stream) {
    const float* x     = (const float*)d_in[0];
    const int*   sizes = (const int*)d_in[1];
    const int*   offy  = (const int*)d_in[2];
    const int*   offx  = (const int*)d_in[3];
    float* out = (float*)d_out;

    make_cutouts_kernel<<<NBLOCKS, 256, 0, stream>>>(x, sizes, offy, offx, out);
}

// Round 2
// 236.497 us; speedup vs baseline: 1.0850x; 1.0338x over previous
//
#include <hip/hip_runtime.h>

// MakeCutouts: 32 cutouts of (8,3,512,512) fp32 -> adaptive avg pool 224x224.
//
// R5: R4 was LDS-pipe bound (~7 ds-reads/pixel for the wp x wq window gather,
// VALUBusy only 43%). Fold the VERTICAL reduction into staging: each staging
// task loads the wp (<=4) input rows of one output row straight from global
// (L2/L3-served), sums + scales by 1/wp in registers, writes ONE 512-wide row
// per output row to LDS. Pool phase then gathers only the horizontal window:
// 2 ds instrs/pixel (ds_read2_b32 pairs) instead of ~7, no vertical cndmask
// chain. TP=8 output rows/block -> tile 16.4 KB, 8 blocks/CU = 32 waves.
// One barrier per block. Pool threads own a fixed column q=tid (<224): bin
// params computed once per thread, no tables.

constexpr int OUTSZ = 224;
constexpr int BB    = 8;
constexpr int CC    = 3;
constexpr int HH    = 512;
constexpr int WW    = 512;
constexpr int CUTN  = 32;

constexpr int TP     = 8;            // output rows per block
constexpr int NBAND  = OUTSZ / TP;   // 28
// tile rows 0..7, horizontal masked reads reach col x0+sq+3 <= 514 -> pad 8
constexpr int LDSF   = TP * WW + 8;  // 4104 floats = 16416 B
constexpr int NBLOCKS = CUTN * BB * CC * NBAND;  // 21504

__device__ __forceinline__ float inv_of(int w) {
    return (w == 1) ? 1.0f : (w == 2) ? 0.5f
         : (w == 3) ? (1.0f / 3.0f) : 0.25f;
}

// Pool all TP rows for one output column q. tile row k already holds the
// vertically-averaged row for output row p0+k; only the horizontal window
// [sq, sq+wq) remains. Masked lanes select z (no garbage propagation; reads
// stay inside the padded tile).
template <int WIN>
__device__ __forceinline__ void pool_cols(const float* __restrict__ tile,
                                          float* __restrict__ outp,
                                          int base, int wq, float invq)
{
    float z = 0.0f;
#pragma unroll
    for (int k = 0; k < TP; ++k) {
        const float* tr = tile + k * WW + base;
        float s = tr[0];  // adjacent cols -> compiler merges to ds_read2_b32
#pragma unroll
        for (int m = 1; m < WIN; ++m)
            s += (wq > m) ? tr[m] : z;
        outp[(size_t)k * OUTSZ] = s * invq;
    }
}

__global__ __launch_bounds__(256, 8) void make_cutouts_kernel(
    const float* __restrict__ x,
    const int*   __restrict__ sizes,
    const int*   __restrict__ offy,
    const int*   __restrict__ offx,
    float*       __restrict__ out)
{
    __shared__ float tile[LDSF];

    int gid = blockIdx.x;
    int tb  = gid % NBAND;  int t = gid / NBAND;
    int c   = t % CC;       t /= CC;
    int b   = t % BB;
    int i   = t / BB;

    // block-uniform per-cutout params -> scalar broadcast
    int S  = sizes[i];
    int y0 = offy[i];
    int x0 = offx[i];
    int p0 = tb * TP;
    int tid = threadIdx.x;

    const float* plane = x + (size_t)((b * CC + c) * HH + y0) * WW;
    float4* tile4 = (float4*)tile;

    // ---- stage: 8 output rows x 128 float4 = 1024 tasks, 4 per thread.
    // Task (k, c4): vertical sum of rows [rs, rs+wp) at cols [4c4, 4c4+4),
    // scaled by 1/wp. k is wave-uniform (u>>7) -> wp branches are scalar.
#pragma unroll
    for (int j = 0; j < 4; ++j) {
        int u  = tid + 256 * j;
        int k  = u >> 7;          // 0..7
        int c4 = u & 127;
        int p  = p0 + k;
        int rs = (p * S) / OUTSZ;
        int wp = ((p + 1) * S + OUTSZ - 1) / OUTSZ - rs;   // 1..4
        const float4* rp = (const float4*)(plane + (size_t)rs * WW) + c4;
        float4 a = rp[0];
        float4 v1, v2, v3;
        if (wp > 1) v1 = rp[128];
        if (wp > 2) v2 = rp[256];
        if (wp > 3) v3 = rp[384];
        if (wp > 1) { a.x += v1.x; a.y += v1.y; a.z += v1.z; a.w += v1.w; }
        if (wp > 2) { a.x += v2.x; a.y += v2.y; a.z += v2.z; a.w += v2.w; }
        if (wp > 3) { a.x += v3.x; a.y += v3.y; a.z += v3.z; a.w += v3.w; }
        float iv = inv_of(wp);
        a.x *= iv; a.y *= iv; a.z *= iv; a.w *= iv;
        tile4[k * 128 + c4] = a;   // adjacent lanes adjacent float4: no conflicts
    }
    __syncthreads();

    // ---- pool: thread t (<224) owns output column q = t for all 8 rows.
    if (tid < OUTSZ) {
        int q  = tid;
        int sq = (q * S) / OUTSZ;
        int wq = ((q + 1) * S + OUTSZ - 1) / OUTSZ - sq;   // 1..4
        float invq = inv_of(wq);
        float* outp = out
            + ((size_t)((i * BB + b) * CC + c) * OUTSZ + p0) * OUTSZ + q;
        if (S <= 2 * OUTSZ)   // block-uniform: max bin width 3
            pool_cols<3>(tile, outp, x0 + sq, wq, invq);
        else                  // S in (448,512): max bin width 4
            pool_cols<4>(tile, outp, x0 + sq, wq, invq);
    }
}

extern "C" void kernel_launch(void* const* d_in, const int* in_sizes, int n_in,
                              void* d_out, int out_size, void* d_ws, size_t ws_size,
                              hipStream_t stream) {
    const float* x     = (const float*)d_in[0];
    const int*   sizes = (const int*)d_in[1];
    const int*   offy  = (const int*)d_in[2];
    const int*   offx  = (const int*)d_in[3];
    float* out = (float*)d_out;

    make_cutouts_kernel<<<NBLOCKS, 256, 0, stream>>>(x, sizes, offy, offx, out);
}

// Round 3
// 196.307 us; speedup vs baseline: 1.3071x; 1.2047x over previous
//
#include <hip/hip_runtime.h>

// MakeCutouts: 32 cutouts of (8,3,512,512) fp32 -> adaptive avg pool 224x224.
//
// R6: R5 collapsed LDS traffic but dur stuck at 103us: FETCH_SIZE=272MB vs a
// 24MB input (11x L2-miss amplification). Cross-cutout reuse of the same
// (b,c) plane is lost because all blocks of cutout i run before cutout i+1
// revisits the plane, and plane blocks spray across all 8 XCD L2s.
// Fix: reorder work as (plane, cutout, band) + bijective XCD chunk swizzle
// (21504 = 8*2688): XCD k owns planes [3k,3k+3) -- a 1MB plane stays hot in
// its 4MB L2 while all 32 cutouts' bands read it. Compute core unchanged
// from R5 (vertical reduce in staging, 2 ds instr/pixel horizontal pool).

constexpr int OUTSZ = 224;
constexpr int BB    = 8;
constexpr int CC    = 3;
constexpr int HH    = 512;
constexpr int WW    = 512;
constexpr int CUTN  = 32;

constexpr int TP     = 8;            // output rows per block
constexpr int NBAND  = OUTSZ / TP;   // 28
constexpr int LDSF   = TP * WW + 8;  // 4104 floats = 16416 B
constexpr int NPLANE = BB * CC;                    // 24
constexpr int WPP    = CUTN * NBAND;               // work per plane = 896
constexpr int NBLOCKS = NPLANE * WPP;              // 21504 = 8 * 2688
constexpr int NXCD   = 8;
constexpr int CHUNK  = NBLOCKS / NXCD;             // 2688 = 3 planes * 896

__device__ __forceinline__ float inv_of(int w) {
    return (w == 1) ? 1.0f : (w == 2) ? 0.5f
         : (w == 3) ? (1.0f / 3.0f) : 0.25f;
}

// Pool all TP rows for one output column q. tile row k already holds the
// vertically-averaged row for output row p0+k; only the horizontal window
// [sq, sq+wq) remains. Masked lanes select z (no garbage propagation; reads
// stay inside the padded tile).
template <int WIN>
__device__ __forceinline__ void pool_cols(const float* __restrict__ tile,
                                          float* __restrict__ outp,
                                          int base, int wq, float invq)
{
    float z = 0.0f;
#pragma unroll
    for (int k = 0; k < TP; ++k) {
        const float* tr = tile + k * WW + base;
        float s = tr[0];  // adjacent cols -> compiler merges to ds_read2_b32
#pragma unroll
        for (int m = 1; m < WIN; ++m)
            s += (wq > m) ? tr[m] : z;
        outp[(size_t)k * OUTSZ] = s * invq;
    }
}

__global__ __launch_bounds__(256, 8) void make_cutouts_kernel(
    const float* __restrict__ x,
    const int*   __restrict__ sizes,
    const int*   __restrict__ offy,
    const int*   __restrict__ offx,
    float*       __restrict__ out)
{
    __shared__ float tile[LDSF];

    // ---- bijective XCD chunk swizzle: dispatch round-robins XCDs, so
    // gid%8 = XCD id. XCD k gets contiguous work [k*CHUNK, (k+1)*CHUNK):
    // 3 planes, all cutouts -> 1MB plane resident in its private L2.
    int gid = blockIdx.x;
    int w   = (gid % NXCD) * CHUNK + gid / NXCD;

    // decode work = (plane, cutout, band); band fastest, plane slowest
    int plane = w / WPP;          // 0..23  (= b*CC + c)
    int rest  = w - plane * WPP;
    int i     = rest / NBAND;     // cutout 0..31
    int tb    = rest - i * NBAND; // band 0..27
    int b     = plane / CC;
    int c     = plane - b * CC;

    // block-uniform per-cutout params -> scalar broadcast
    int S  = sizes[i];
    int y0 = offy[i];
    int x0 = offx[i];
    int p0 = tb * TP;
    int tid = threadIdx.x;

    const float* plane_p = x + (size_t)(plane * HH + y0) * WW;
    float4* tile4 = (float4*)tile;

    // ---- stage: 8 output rows x 128 float4 = 1024 tasks, 4 per thread.
    // Task (k, c4): vertical sum of rows [rs, rs+wp) at cols [4c4, 4c4+4),
    // scaled by 1/wp. k is wave-uniform (u>>7) -> wp branches are scalar.
#pragma unroll
    for (int j = 0; j < 4; ++j) {
        int u  = tid + 256 * j;
        int k  = u >> 7;          // 0..7
        int c4 = u & 127;
        int p  = p0 + k;
        int rs = (p * S) / OUTSZ;
        int wp = ((p + 1) * S + OUTSZ - 1) / OUTSZ - rs;   // 1..4
        const float4* rp = (const float4*)(plane_p + (size_t)rs * WW) + c4;
        float4 a = rp[0];
        float4 v1, v2, v3;
        if (wp > 1) v1 = rp[128];
        if (wp > 2) v2 = rp[256];
        if (wp > 3) v3 = rp[384];
        if (wp > 1) { a.x += v1.x; a.y += v1.y; a.z += v1.z; a.w += v1.w; }
        if (wp > 2) { a.x += v2.x; a.y += v2.y; a.z += v2.z; a.w += v2.w; }
        if (wp > 3) { a.x += v3.x; a.y += v3.y; a.z += v3.z; a.w += v3.w; }
        float iv = inv_of(wp);
        a.x *= iv; a.y *= iv; a.z *= iv; a.w *= iv;
        tile4[k * 128 + c4] = a;   // adjacent lanes adjacent float4: no conflicts
    }
    __syncthreads();

    // ---- pool: thread t (<224) owns output column q = t for all 8 rows.
    if (tid < OUTSZ) {
        int q  = tid;
        int sq = (q * S) / OUTSZ;
        int wq = ((q + 1) * S + OUTSZ - 1) / OUTSZ - sq;   // 1..4
        float invq = inv_of(wq);
        float* outp = out
            + ((size_t)((i * BB + b) * CC + c) * OUTSZ + p0) * OUTSZ + q;
        if (S <= 2 * OUTSZ)   // block-uniform: max bin width 3
            pool_cols<3>(tile, outp, x0 + sq, wq, invq);
        else                  // S in (448,512]: max bin width 4
            pool_cols<4>(tile, outp, x0 + sq, wq, invq);
    }
}

extern "C" void kernel_launch(void* const* d_in, const int* in_sizes, int n_in,
                              void* d_out, int out_size, void* d_ws, size_t ws_size,
                              hipStream_t stream) {
    const float* x     = (const float*)d_in[0];
    const int*   sizes = (const int*)d_in[1];
    const int*   offy  = (const int*)d_in[2];
    const int*   offx  = (const int*)d_in[3];
    float* out = (float*)d_out;

    make_cutouts_kernel<<<NBLOCKS, 256, 0, stream>>>(x, sizes, offy, offx, out);
}

// Round 4
// 194.033 us; speedup vs baseline: 1.3224x; 1.0117x over previous
//
#include <hip/hip_runtime.h>

// MakeCutouts: 32 cutouts of (8,3,512,512) fp32 -> adaptive avg pool 224x224.
//
// R7: R6 (XCD-chunked order) got per-dispatch to ~85us; remaining excess is
// VALU instruction count in the stage phase, where the compiler can't prove
// k = wave-uniform and emits the rs/wp magic-div chains, addressing and
// branch masks as vector ops x4 per thread. Fix:
//  - readfirstlane(wave id) -> rs/wp/row-base computed on SALU, conditional
//    row loads become uniform s_cbranch (no exec masks).
//  - vertical adds on f32x4 ext_vector -> v_pk_add_f32 (packed fp32, 2x).
//  - pool phase: per-thread weight vector w[m] = (wq>m ? invq : 0), window
//    becomes a 3/4-term fma dot (no cndmask chain, invq folded into weights).
//    Weight-0 lanes read (finite) neighbor data; the 8-float end pad is
//    zeroed each block to kill the 0*NaN hazard on row 7.
// Work order/grid unchanged from R6: (plane, cutout, band) + bijective XCD
// chunk swizzle, 21504 blocks x 256, tile 16.4 KB -> 8 blocks/CU.

typedef float f32x4 __attribute__((ext_vector_type(4)));

constexpr int OUTSZ = 224;
constexpr int BB    = 8;
constexpr int CC    = 3;
constexpr int HH    = 512;
constexpr int WW    = 512;
constexpr int CUTN  = 32;

constexpr int TP     = 8;            // output rows per block
constexpr int NBAND  = OUTSZ / TP;   // 28
constexpr int LDSF   = TP * WW + 8;  // 4104 floats = 16416 B
constexpr int NPLANE = BB * CC;                    // 24
constexpr int WPP    = CUTN * NBAND;               // work per plane = 896
constexpr int NBLOCKS = NPLANE * WPP;              // 21504 = 8 * 2688
constexpr int NXCD   = 8;
constexpr int CHUNK  = NBLOCKS / NXCD;             // 2688 = 3 planes * 896

// Pool all TP rows for one output column q as a dot product with weights
// {invq or 0}. tile row k holds the vertically-averaged (already /wp) row.
// Reads past the window have weight 0; data there is finite (staged rows /
// zeroed pad), so fma with 0 is exact.
template <int WIN>
__device__ __forceinline__ void pool_cols(const float* __restrict__ tile,
                                          float* __restrict__ outp,
                                          int base, const float* __restrict__ w)
{
#pragma unroll
    for (int k = 0; k < TP; ++k) {
        const float* tr = tile + k * WW + base;
        float s = tr[0] * w[0];              // adjacent cols -> ds_read2_b32
        s = fmaf(tr[1], w[1], s);
        s = fmaf(tr[2], w[2], s);
        if (WIN == 4) s = fmaf(tr[3], w[3], s);
        outp[(size_t)k * OUTSZ] = s;
    }
}

__global__ __launch_bounds__(256, 8) void make_cutouts_kernel(
    const float* __restrict__ x,
    const int*   __restrict__ sizes,
    const int*   __restrict__ offy,
    const int*   __restrict__ offx,
    float*       __restrict__ out)
{
    __shared__ float tile[LDSF];

    // ---- bijective XCD chunk swizzle (21504 = 8*2688): XCD k owns planes
    // [3k, 3k+3); a 1MB plane stays hot in its private 4MB L2 across cutouts.
    int gid = blockIdx.x;
    int w   = (gid % NXCD) * CHUNK + gid / NXCD;

    // decode work = (plane, cutout, band)
    int plane = w / WPP;          // 0..23  (= b*CC + c)
    int rest  = w - plane * WPP;
    int i     = rest / NBAND;     // cutout 0..31
    int tb    = rest - i * NBAND; // band 0..27
    int b     = plane / CC;
    int c     = plane - b * CC;

    // block-uniform per-cutout params -> scalar broadcast
    int S  = sizes[i];
    int y0 = offy[i];
    int x0 = offx[i];
    int p0 = tb * TP;
    int tid = threadIdx.x;

    const float* plane_p = x + (size_t)(plane * HH + y0) * WW;

    // zero the end pad: row 7's masked reads can touch it; LDS is stale
    // across blocks and 0 * garbage(NaN) would poison the fma dot.
    if (tid < 8) tile[TP * WW + tid] = 0.0f;

    // ---- stage (scalarized): wave wv handles rows {(wv>>1) + 2j}, column
    // half wv&1. k/rs/wp/row-base are provably wave-uniform -> SALU + uniform
    // branches; only the lane offset and the packed adds stay on VALU.
    int wv   = __builtin_amdgcn_readfirstlane(tid >> 6);  // 0..3
    int lane = tid & 63;
    int vo   = ((wv & 1) << 6) + lane;    // float4 col index 0..127
    f32x4* tile4 = (f32x4*)tile;
#pragma unroll
    for (int j = 0; j < 4; ++j) {
        int k  = (wv >> 1) + 2 * j;       // scalar 0..7
        int p  = p0 + k;
        int rs = (p * S) / OUTSZ;                          // scalar magic div
        int wp = ((p + 1) * S + OUTSZ - 1) / OUTSZ - rs;   // 1..4, scalar
        const f32x4* rp = (const f32x4*)(plane_p + (size_t)rs * WW);
        f32x4 a = rp[vo];
        f32x4 v1, v2, v3;
        bool b1 = wp > 1, b2 = wp > 2, b3 = wp > 3;        // uniform
        if (b1) v1 = rp[vo + 128];
        if (b2) v2 = rp[vo + 256];
        if (b3) v3 = rp[vo + 384];
        if (b1) a += v1;                  // v_pk_add_f32 pairs
        if (b2) a += v2;
        if (b3) a += v3;
        float iv = (wp == 1) ? 1.0f : (wp == 2) ? 0.5f
                 : (wp == 3) ? (1.0f / 3.0f) : 0.25f;      // scalar cselect
        a *= iv;
        tile4[k * 128 + vo] = a;          // adjacent lanes -> ds_write_b128
    }
    __syncthreads();

    // ---- pool: thread t (<224) owns output column q = t for all 8 rows.
    if (tid < OUTSZ) {
        int q  = tid;
        int sq = (q * S) / OUTSZ;
        int wq = ((q + 1) * S + OUTSZ - 1) / OUTSZ - sq;   // 1..4
        float invq = (wq == 1) ? 1.0f : (wq == 2) ? 0.5f
                   : (wq == 3) ? (1.0f / 3.0f) : 0.25f;
        float wt[4];
        wt[0] = invq;
        wt[1] = (wq > 1) ? invq : 0.0f;
        wt[2] = (wq > 2) ? invq : 0.0f;
        wt[3] = (wq > 3) ? invq : 0.0f;
        float* outp = out
            + ((size_t)((i * BB + b) * CC + c) * OUTSZ + p0) * OUTSZ + q;
        if (S <= 2 * OUTSZ)   // block-uniform: max bin width 3
            pool_cols<3>(tile, outp, x0 + sq, wt);
        else                  // S in (448,512]: max bin width 4
            pool_cols<4>(tile, outp, x0 + sq, wt);
    }
}

extern "C" void kernel_launch(void* const* d_in, const int* in_sizes, int n_in,
                              void* d_out, int out_size, void* d_ws, size_t ws_size,
                              hipStream_t stream) {
    const float* x     = (const float*)d_in[0];
    const int*   sizes = (const int*)d_in[1];
    const int*   offy  = (const int*)d_in[2];
    const int*   offx  = (const int*)d_in[3];
    float* out = (float*)d_out;

    make_cutouts_kernel<<<NBLOCKS, 256, 0, stream>>>(x, sizes, offy, offx, out);
}